// Round 13
// baseline (278202.808 us; speedup 1.0000x reference)
//
#include <hip/hip_runtime.h>
#include <hip/hip_bf16.h>
#include <stdint.h>
#include <stddef.h>

// ============================================================================
// ROUND 13: OUTPUT DTYPE FIX — d_out is FLOAT32 (reference returns f32; the
// bf16 read-branch in the harness only applies to bf16-output refs).
// All 12 prior failures explained by writing bf16 halfwords into an f32 buffer.
// Masks: modern JAX default (partitionable x32, threefry core hand-verified).
// memory_lengths: int32 (proven by R10's auto-detect).
// ============================================================================
#define SPLIT_MODE 0
#define BITS_MODE  0

#define B_    64
#define TIN   200
#define TOUT  400
#define ENC   512
#define NMEL  80
#define PRE   256
#define RNN   1024
#define G4    4096
#define ATTD  128
#define LOCF  32
#define LOCK  31
#define MSIZE 6569984u   // 401*64*256

// ---------------- threefry2x32-20 (hand-verified vs split(PRNGKey(0))) ----------------
__host__ __device__ inline void tf2x32(uint32_t k0, uint32_t k1, uint32_t x0, uint32_t x1,
                                       uint32_t* o0, uint32_t* o1) {
  uint32_t k2 = k0 ^ k1 ^ 0x1BD11BDAu;
#define TFROT(v, r) (((v) << (r)) | ((v) >> (32 - (r))))
#define TFR(r) { x0 += x1; x1 = TFROT(x1, r); x1 ^= x0; }
  x0 += k0; x1 += k1;
  TFR(13) TFR(15) TFR(26) TFR(6)  x0 += k1; x1 += k2 + 1u;
  TFR(17) TFR(29) TFR(16) TFR(24) x0 += k2; x1 += k0 + 2u;
  TFR(13) TFR(15) TFR(26) TFR(6)  x0 += k0; x1 += k1 + 3u;
  TFR(17) TFR(29) TFR(16) TFR(24) x0 += k1; x1 += k2 + 4u;
  TFR(13) TFR(15) TFR(26) TFR(6)  x0 += k2; x1 += k0 + 5u;
  *o0 = x0; *o1 = x1;
#undef TFR
#undef TFROT
}

__device__ inline bool tf_keep(uint32_t ka, uint32_t kb, uint32_t idx) {
#if BITS_MODE == 0
  uint32_t a, b; tf2x32(ka, kb, 0u, idx, &a, &b);
  return (((a ^ b) >> 31) == 0u);      // partitionable x32: bits = o0 ^ o1
#else
  const uint32_t HALF = MSIZE / 2u;
  uint32_t a, b;
  if (idx < HALF) { tf2x32(ka, kb, idx, idx + HALF, &a, &b); return ((a >> 31) == 0u); }
  else            { tf2x32(ka, kb, idx - HALF, idx, &a, &b); return ((b >> 31) == 0u); }
#endif
}

__device__ inline float sigf(float x) { return 1.f / (1.f + __expf(-x)); }

// ---------------- workspace layout (floats) — ~10 MB ----------------
static const size_t OFF_PM   = 0;
static const size_t OFF_XS   = OFF_PM   + (size_t)B_ * TIN * ATTD;
static const size_t OFF_HATT = OFF_XS   + (size_t)B_ * PRE;
static const size_t OFF_CATT = OFF_HATT + (size_t)B_ * RNN;
static const size_t OFF_HDEC = OFF_CATT + (size_t)B_ * RNN;
static const size_t OFF_CDEC = OFF_HDEC + (size_t)B_ * RNN;
static const size_t OFF_CTX  = OFF_CDEC + (size_t)B_ * RNN;
static const size_t OFF_AW   = OFF_CTX  + (size_t)B_ * ENC;
static const size_t OFF_AWC  = OFF_AW   + (size_t)B_ * TIN;
static const size_t OFF_ATTG = OFF_AWC  + (size_t)B_ * TIN;
static const size_t OFF_DECG = OFF_ATTG + (size_t)B_ * G4;

// ---------------- kernels ----------------
__global__ __launch_bounds__(256) void k_init(float* s, int n) {
  int i = blockIdx.x * 256 + threadIdx.x;
  if (i < n) s[i] = 0.f;
}

__global__ __launch_bounds__(256) void k_prenet_step(const float* __restrict__ dec,
    const float* __restrict__ w1, const float* __restrict__ w2, float* __restrict__ xs,
    uint32_t k1a, uint32_t k1b, uint32_t k2a, uint32_t k2b, int t) {
  int b = blockIdx.x, j = threadIdx.x;
  __shared__ __align__(16) float in_s[NMEL];
  __shared__ __align__(16) float h_s[PRE];
  if (j < NMEL) in_s[j] = (t == 0) ? 0.f : dec[((size_t)b * NMEL + j) * TOUT + (t - 1)];
  __syncthreads();
  float a = 0.f;
  {
    const float4* w14 = (const float4*)(w1 + (size_t)j * NMEL);
    const float4* i4  = (const float4*)in_s;
    #pragma unroll
    for (int k = 0; k < NMEL / 4; ++k) {
      float4 w = w14[k], v = i4[k];
      a += w.x * v.x + w.y * v.y + w.z * v.z + w.w * v.w;
    }
  }
  a = fmaxf(a, 0.f);
  uint32_t idx = (uint32_t)((t * 64 + b) * 256 + j);
  a = tf_keep(k1a, k1b, idx) ? a * 2.f : 0.f;
  h_s[j] = a;
  __syncthreads();
  float a2 = 0.f;
  {
    const float4* w24 = (const float4*)(w2 + (size_t)j * PRE);
    const float4* h4  = (const float4*)h_s;
    #pragma unroll 8
    for (int k = 0; k < PRE / 4; ++k) {
      float4 w = w24[k], v = h4[k];
      a2 += w.x * v.x + w.y * v.y + w.z * v.z + w.w * v.w;
    }
  }
  a2 = fmaxf(a2, 0.f);
  a2 = tf_keep(k2a, k2b, idx) ? a2 * 2.f : 0.f;
  xs[((size_t)b << 8) + j] = a2;
}

__global__ __launch_bounds__(128) void k_procmem(const float* __restrict__ memory,
    const float* __restrict__ wmem, float* __restrict__ pm) {
  int b = blockIdx.x / TIN, tt = blockIdx.x % TIN;
  int d = threadIdx.x;
  __shared__ __align__(16) float m_s[ENC];
  for (int k = d; k < ENC; k += 128) m_s[k] = memory[((size_t)b * TIN + tt) * ENC + k];
  __syncthreads();
  float a = 0.f;
  const float4* w4 = (const float4*)(wmem + (size_t)d * ENC);
  const float4* m4 = (const float4*)m_s;
  #pragma unroll 8
  for (int k = 0; k < ENC / 4; ++k) {
    float4 w = w4[k], v = m4[k];
    a += w.x * v.x + w.y * v.y + w.z * v.z + w.w * v.w;
  }
  pm[((size_t)b * TIN + tt) * ATTD + d] = a;
}

__global__ __launch_bounds__(256) void k_attgates(const float* __restrict__ xs,
    const float* __restrict__ ctx, const float* __restrict__ hatt, float* __restrict__ attg,
    const float* __restrict__ wih, const float* __restrict__ whh,
    const float* __restrict__ bih, const float* __restrict__ bhh) {
  int b = blockIdx.y;
  int col = blockIdx.x * 256 + threadIdx.x;
  __shared__ __align__(16) float in_s[PRE + ENC];
  __shared__ __align__(16) float h_s[RNN];
  const float* xr = xs + (size_t)b * PRE;
  for (int k = threadIdx.x; k < PRE + ENC; k += 256)
    in_s[k] = (k < PRE) ? xr[k] : ctx[(size_t)b * ENC + (k - PRE)];
  for (int k = threadIdx.x; k < RNN; k += 256) h_s[k] = hatt[(size_t)b * RNN + k];
  __syncthreads();
  float acc = bih[col] + bhh[col];
  {
    const float4* w4 = (const float4*)(wih + (size_t)col * (PRE + ENC));
    const float4* i4 = (const float4*)in_s;
    #pragma unroll 4
    for (int k = 0; k < (PRE + ENC) / 4; ++k) {
      float4 w = w4[k], v = i4[k];
      acc += w.x * v.x + w.y * v.y + w.z * v.z + w.w * v.w;
    }
  }
  {
    const float4* w4 = (const float4*)(whh + (size_t)col * RNN);
    const float4* h4 = (const float4*)h_s;
    #pragma unroll 4
    for (int k = 0; k < RNN / 4; ++k) {
      float4 w = w4[k], v = h4[k];
      acc += w.x * v.x + w.y * v.y + w.z * v.z + w.w * v.w;
    }
  }
  attg[(size_t)b * G4 + col] = acc;
}

__global__ __launch_bounds__(256) void k_decgates(const float* __restrict__ hatt,
    const float* __restrict__ ctx, const float* __restrict__ hdec, float* __restrict__ decg,
    const float* __restrict__ wih, const float* __restrict__ whh,
    const float* __restrict__ bih, const float* __restrict__ bhh) {
  int b = blockIdx.y;
  int col = blockIdx.x * 256 + threadIdx.x;
  __shared__ __align__(16) float in_s[RNN + ENC];
  __shared__ __align__(16) float h_s[RNN];
  for (int k = threadIdx.x; k < RNN + ENC; k += 256)
    in_s[k] = (k < RNN) ? hatt[(size_t)b * RNN + k] : ctx[(size_t)b * ENC + (k - RNN)];
  for (int k = threadIdx.x; k < RNN; k += 256) h_s[k] = hdec[(size_t)b * RNN + k];
  __syncthreads();
  float acc = bih[col] + bhh[col];
  {
    const float4* w4 = (const float4*)(wih + (size_t)col * (RNN + ENC));
    const float4* i4 = (const float4*)in_s;
    #pragma unroll 4
    for (int k = 0; k < (RNN + ENC) / 4; ++k) {
      float4 w = w4[k], v = i4[k];
      acc += w.x * v.x + w.y * v.y + w.z * v.z + w.w * v.w;
    }
  }
  {
    const float4* w4 = (const float4*)(whh + (size_t)col * RNN);
    const float4* h4 = (const float4*)h_s;
    #pragma unroll 4
    for (int k = 0; k < RNN / 4; ++k) {
      float4 w = w4[k], v = h4[k];
      acc += w.x * v.x + w.y * v.y + w.z * v.z + w.w * v.w;
    }
  }
  decg[(size_t)b * G4 + col] = acc;
}

__global__ __launch_bounds__(256) void k_attention(
    const float* __restrict__ attg, float* __restrict__ hatt, float* __restrict__ catt,
    float* __restrict__ aw, float* __restrict__ awc, float* __restrict__ ctx,
    const float* __restrict__ pm, const float* __restrict__ memory,
    const float* __restrict__ wq, const float* __restrict__ wv,
    const float* __restrict__ wconv, const float* __restrict__ wloc,
    const int* __restrict__ memlen, float* __restrict__ out_align, int t) {
  int b = blockIdx.x, tid = threadIdx.x;
  __shared__ float h_s[RNN];
  __shared__ float aw_s[TIN], awc_s[TIN];
  __shared__ float loc_s[LOCF * TIN];
  __shared__ float pq_s[ATTD];
  __shared__ float e2_s[2 * TIN];
  __shared__ float red[256];

  // finish att LSTM (i,f,g,o)
  for (int r = 0; r < 4; ++r) {
    int j = tid + 256 * r;
    float ig = attg[(size_t)b * G4 + j];
    float fg = attg[(size_t)b * G4 + RNN + j];
    float gg = attg[(size_t)b * G4 + 2 * RNN + j];
    float og = attg[(size_t)b * G4 + 3 * RNN + j];
    float c = sigf(fg) * catt[(size_t)b * RNN + j] + sigf(ig) * tanhf(gg);
    float h = sigf(og) * tanhf(c);
    catt[(size_t)b * RNN + j] = c;
    hatt[(size_t)b * RNN + j] = h;
    h_s[j] = h;
  }
  for (int k = tid; k < TIN; k += 256) { aw_s[k] = aw[(size_t)b * TIN + k]; awc_s[k] = awc[(size_t)b * TIN + k]; }
  __syncthreads();

  // pq = h @ wq.T
  {
    int d = tid & 127, hf = tid >> 7;
    float a = 0.f;
    const float* wr = wq + (size_t)d * RNN + hf * 512;
    const float* hr = h_s + hf * 512;
    #pragma unroll 8
    for (int k = 0; k < 512; ++k) a += hr[k] * wr[k];
    red[tid] = a;
  }
  __syncthreads();
  if (tid < ATTD) pq_s[tid] = red[tid] + red[tid + 128];

  // location conv
  for (int task = tid; task < LOCF * TIN; task += 256) {
    int f = task / TIN, tt = task % TIN;
    float a = 0.f;
    #pragma unroll
    for (int k = 0; k < LOCK; ++k) {
      int s = tt + k - 15;
      if (s >= 0 && s < TIN)
        a += aw_s[s] * wconv[f * (2 * LOCK) + k] + awc_s[s] * wconv[f * (2 * LOCK) + LOCK + k];
    }
    loc_s[task] = a;
  }
  __syncthreads();

  // energies
  for (int task = tid; task < 2 * TIN; task += 256) {
    int hf = task / TIN, tt = task % TIN;
    float acc = 0.f;
    const float* pmr = pm + ((size_t)b * TIN + tt) * ATTD;
    for (int d = hf * 64; d < hf * 64 + 64; ++d) {
      float pl = 0.f;
      #pragma unroll
      for (int f = 0; f < LOCF; ++f) pl += loc_s[f * TIN + tt] * wloc[d * LOCF + f];
      acc += tanhf(pmr[d] + pq_s[d] + pl) * wv[d];
    }
    e2_s[task] = acc;
  }
  __syncthreads();

  // masked softmax
  int len = memlen[b];
  float ev = -3.0e38f;
  if (tid < TIN) ev = (tid < len) ? (e2_s[tid] + e2_s[TIN + tid]) : -1.0e9f;
  red[tid] = ev;
  __syncthreads();
  for (int s = 128; s > 0; s >>= 1) { if (tid < s) red[tid] = fmaxf(red[tid], red[tid + s]); __syncthreads(); }
  float m = red[0];
  __syncthreads();
  float p = (tid < TIN) ? __expf(ev - m) : 0.f;
  red[tid] = p;
  __syncthreads();
  for (int s = 128; s > 0; s >>= 1) { if (tid < s) red[tid] += red[tid + s]; __syncthreads(); }
  float inv = 1.f / red[0];
  __syncthreads();
  if (tid < TIN) {
    float a = p * inv;
    aw[(size_t)b * TIN + tid] = a;
    awc[(size_t)b * TIN + tid] = awc_s[tid] + a;
    out_align[((size_t)b * TOUT + t) * TIN + tid] = a;   // FLOAT32 output
    aw_s[tid] = a;
  }
  __syncthreads();

  // context
  for (int ee = tid; ee < ENC; ee += 256) {
    float a = 0.f;
    for (int tt = 0; tt < TIN; ++tt) a += aw_s[tt] * memory[((size_t)b * TIN + tt) * ENC + ee];
    ctx[(size_t)b * ENC + ee] = a;
  }
}

__global__ __launch_bounds__(256) void k_outphase(
    const float* __restrict__ decg, const float* __restrict__ ctx,
    float* __restrict__ hdec, float* __restrict__ cdec,
    const float* __restrict__ wproj, const float* __restrict__ bproj,
    const float* __restrict__ wgate, const float* __restrict__ bgate,
    float* __restrict__ out, int t) {
  int b = blockIdx.x, tid = threadIdx.x;
  __shared__ float dha_s[RNN + ENC];
  __shared__ float red[256];
  for (int r = 0; r < 4; ++r) {
    int j = tid + 256 * r;
    float ig = decg[(size_t)b * G4 + j];
    float fg = decg[(size_t)b * G4 + RNN + j];
    float gg = decg[(size_t)b * G4 + 2 * RNN + j];
    float og = decg[(size_t)b * G4 + 3 * RNN + j];
    float c = sigf(fg) * cdec[(size_t)b * RNN + j] + sigf(ig) * tanhf(gg);
    float h = sigf(og) * tanhf(c);
    cdec[(size_t)b * RNN + j] = c;
    hdec[(size_t)b * RNN + j] = h;
    dha_s[j] = h;
  }
  for (int k = tid; k < ENC; k += 256) dha_s[RNN + k] = ctx[(size_t)b * ENC + k];
  __syncthreads();
  float mp = 0.f;
  if (tid < 2 * NMEL) {
    int m = tid % NMEL, hf = tid / NMEL;
    const float* wr = wproj + (size_t)m * (RNN + ENC) + hf * 768;
    const float* dr = dha_s + hf * 768;
    #pragma unroll 8
    for (int k = 0; k < 768; ++k) mp += dr[k] * wr[k];
  }
  red[tid] = mp;
  __syncthreads();
  if (tid < NMEL) {
    float mel = red[tid] + red[tid + NMEL] + bproj[tid];
    out[((size_t)b * NMEL + tid) * TOUT + t] = mel;       // FLOAT32 output
  }
  __syncthreads();
  float g = 0.f;
  for (int k = tid; k < RNN + ENC; k += 256) g += dha_s[k] * wgate[k];
  red[tid] = g;
  __syncthreads();
  for (int s = 128; s > 0; s >>= 1) { if (tid < s) red[tid] += red[tid + s]; __syncthreads(); }
  if (tid == 0) out[(size_t)2048000 + (size_t)b * TOUT + t] = red[0] + bgate[0];  // FLOAT32
}

// ---------------- host launcher (full 400 steps) ----------------
extern "C" void kernel_launch(void* const* d_in, const int* in_sizes, int n_in,
                              void* d_out, int out_size, void* d_ws, size_t ws_size,
                              hipStream_t stream) {
  (void)in_sizes; (void)n_in; (void)out_size; (void)ws_size;
  const float* memory  = (const float*)d_in[0];
  const float* dec     = (const float*)d_in[1];
  const int*   mlen    = (const int*)d_in[2];
  const float* w1      = (const float*)d_in[3];
  const float* w2      = (const float*)d_in[4];
  const float* wih_att = (const float*)d_in[5];
  const float* whh_att = (const float*)d_in[6];
  const float* bih_att = (const float*)d_in[7];
  const float* bhh_att = (const float*)d_in[8];
  const float* wq      = (const float*)d_in[9];
  const float* wmem    = (const float*)d_in[10];
  const float* wv      = (const float*)d_in[11];
  const float* wconv   = (const float*)d_in[12];
  const float* wloc    = (const float*)d_in[13];
  const float* wih_dec = (const float*)d_in[14];
  const float* whh_dec = (const float*)d_in[15];
  const float* bih_dec = (const float*)d_in[16];
  const float* bhh_dec = (const float*)d_in[17];
  const float* wproj   = (const float*)d_in[18];
  const float* bproj   = (const float*)d_in[19];
  const float* wgate   = (const float*)d_in[20];
  const float* bgate   = (const float*)d_in[21];
  float* out = (float*)d_out;                       // FLOAT32 output buffer
  float* ws  = (float*)d_ws;

  // dropout keys from jax.random.split(jax.random.key(42)); key = (0, 42)
  uint32_t dk1a, dk1b, dk2a, dk2b;
#if SPLIT_MODE == 0
  tf2x32(0u, 42u, 0u, 0u, &dk1a, &dk1b);
  tf2x32(0u, 42u, 0u, 1u, &dk2a, &dk2b);
#else
  uint32_t a0, b0, a1, b1;
  tf2x32(0u, 42u, 0u, 2u, &a0, &b0);
  tf2x32(0u, 42u, 1u, 3u, &a1, &b1);
  dk1a = a0; dk1b = a1; dk2a = b0; dk2b = b1;
#endif

  float* pm   = ws + OFF_PM;
  float* xs   = ws + OFF_XS;
  float* hatt = ws + OFF_HATT; float* catt = ws + OFF_CATT;
  float* hdec = ws + OFF_HDEC; float* cdec = ws + OFF_CDEC;
  float* ctxp = ws + OFF_CTX;
  float* aw   = ws + OFF_AW;   float* awc  = ws + OFF_AWC;
  float* attg = ws + OFF_ATTG; float* decg = ws + OFF_DECG;

  int nstate = B_ * (PRE + 4 * RNN + ENC + 2 * TIN);   // xs..awc contiguous
  k_init<<<(nstate + 255) / 256, 256, 0, stream>>>(xs, nstate);
  k_procmem<<<B_ * TIN, 128, 0, stream>>>(memory, wmem, pm);

  float* out_align = out + 2073600;   // 64*80*400 + 64*400 (float elements)
  for (int t = 0; t < TOUT; ++t) {
    k_prenet_step<<<B_, 256, 0, stream>>>(dec, w1, w2, xs, dk1a, dk1b, dk2a, dk2b, t);
    k_attgates<<<dim3(16, B_), 256, 0, stream>>>(xs, ctxp, hatt, attg,
                                                 wih_att, whh_att, bih_att, bhh_att);
    k_attention<<<B_, 256, 0, stream>>>(attg, hatt, catt, aw, awc, ctxp, pm, memory,
                                        wq, wv, wconv, wloc, mlen, out_align, t);
    k_decgates<<<dim3(16, B_), 256, 0, stream>>>(hatt, ctxp, hdec, decg,
                                                 wih_dec, whh_dec, bih_dec, bhh_dec);
    k_outphase<<<B_, 256, 0, stream>>>(decg, ctxp, hdec, cdec,
                                       wproj, bproj, wgate, bgate, out, t);
  }
}

// Round 14
// 116424.243 us; speedup vs baseline: 2.3896x; 2.3896x over previous
//
#include <hip/hip_runtime.h>
#include <hip/hip_bf16.h>
#include <stdint.h>
#include <stddef.h>

// ============================================================================
// ROUND 14: batched-GEMM gate kernels. R13 passed (absmax 1.95e-3) but ran
// 278 ms = HBM-bound on 64x redundant weight reads (4.6 GB/step, matches
// measured BW exactly). New k_gates: weights read ONCE/step, K-split 16 into
// deterministic partials, 256 blocks (all CUs), 8x8 register tiles.
// ============================================================================
#define SPLIT_MODE 0
#define BITS_MODE  0
#define KSPLIT 16

#define B_    64
#define TIN   200
#define TOUT  400
#define ENC   512
#define NMEL  80
#define PRE   256
#define RNN   1024
#define G4    4096
#define ATTD  128
#define LOCF  32
#define LOCK  31
#define MSIZE 6569984u   // 401*64*256

// ---------------- threefry2x32-20 (hand-verified vs split(PRNGKey(0))) ----------------
__host__ __device__ inline void tf2x32(uint32_t k0, uint32_t k1, uint32_t x0, uint32_t x1,
                                       uint32_t* o0, uint32_t* o1) {
  uint32_t k2 = k0 ^ k1 ^ 0x1BD11BDAu;
#define TFROT(v, r) (((v) << (r)) | ((v) >> (32 - (r))))
#define TFR(r) { x0 += x1; x1 = TFROT(x1, r); x1 ^= x0; }
  x0 += k0; x1 += k1;
  TFR(13) TFR(15) TFR(26) TFR(6)  x0 += k1; x1 += k2 + 1u;
  TFR(17) TFR(29) TFR(16) TFR(24) x0 += k2; x1 += k0 + 2u;
  TFR(13) TFR(15) TFR(26) TFR(6)  x0 += k0; x1 += k1 + 3u;
  TFR(17) TFR(29) TFR(16) TFR(24) x0 += k1; x1 += k2 + 4u;
  TFR(13) TFR(15) TFR(26) TFR(6)  x0 += k2; x1 += k0 + 5u;
  *o0 = x0; *o1 = x1;
#undef TFR
#undef TFROT
}

__device__ inline bool tf_keep(uint32_t ka, uint32_t kb, uint32_t idx) {
#if BITS_MODE == 0
  uint32_t a, b; tf2x32(ka, kb, 0u, idx, &a, &b);
  return (((a ^ b) >> 31) == 0u);      // partitionable x32: bits = o0 ^ o1
#else
  const uint32_t HALF = MSIZE / 2u;
  uint32_t a, b;
  if (idx < HALF) { tf2x32(ka, kb, idx, idx + HALF, &a, &b); return ((a >> 31) == 0u); }
  else            { tf2x32(ka, kb, idx - HALF, idx, &a, &b); return ((b >> 31) == 0u); }
#endif
}

__device__ inline float sigf(float x) { return 1.f / (1.f + __expf(-x)); }

// ---------------- workspace layout (floats) — ~25 MB ----------------
static const size_t OFF_PM   = 0;                                    // 64*200*128
static const size_t OFF_XS   = OFF_PM   + (size_t)B_ * TIN * ATTD;   // 64*256
static const size_t OFF_HATT = OFF_XS   + (size_t)B_ * PRE;
static const size_t OFF_CATT = OFF_HATT + (size_t)B_ * RNN;
static const size_t OFF_HDEC = OFF_CATT + (size_t)B_ * RNN;
static const size_t OFF_CDEC = OFF_HDEC + (size_t)B_ * RNN;
static const size_t OFF_CTX  = OFF_CDEC + (size_t)B_ * RNN;
static const size_t OFF_AW   = OFF_CTX  + (size_t)B_ * ENC;
static const size_t OFF_AWC  = OFF_AW   + (size_t)B_ * TIN;
static const size_t OFF_PART = OFF_AWC  + (size_t)B_ * TIN;          // 16*64*4096
// end = OFF_PART + 4,194,304  (total ~6.17M floats ~ 24.7 MB)

// ---------------- kernels ----------------
__global__ __launch_bounds__(256) void k_init(float* s, int n) {
  int i = blockIdx.x * 256 + threadIdx.x;
  if (i < n) s[i] = 0.f;
}

__global__ __launch_bounds__(256) void k_prenet_step(const float* __restrict__ dec,
    const float* __restrict__ w1, const float* __restrict__ w2, float* __restrict__ xs,
    uint32_t k1a, uint32_t k1b, uint32_t k2a, uint32_t k2b, int t) {
  int b = blockIdx.x, j = threadIdx.x;
  __shared__ __align__(16) float in_s[NMEL];
  __shared__ __align__(16) float h_s[PRE];
  if (j < NMEL) in_s[j] = (t == 0) ? 0.f : dec[((size_t)b * NMEL + j) * TOUT + (t - 1)];
  __syncthreads();
  float a = 0.f;
  {
    const float4* w14 = (const float4*)(w1 + (size_t)j * NMEL);
    const float4* i4  = (const float4*)in_s;
    #pragma unroll
    for (int k = 0; k < NMEL / 4; ++k) {
      float4 w = w14[k], v = i4[k];
      a += w.x * v.x + w.y * v.y + w.z * v.z + w.w * v.w;
    }
  }
  a = fmaxf(a, 0.f);
  uint32_t idx = (uint32_t)((t * 64 + b) * 256 + j);
  a = tf_keep(k1a, k1b, idx) ? a * 2.f : 0.f;
  h_s[j] = a;
  __syncthreads();
  float a2 = 0.f;
  {
    const float4* w24 = (const float4*)(w2 + (size_t)j * PRE);
    const float4* h4  = (const float4*)h_s;
    #pragma unroll 8
    for (int k = 0; k < PRE / 4; ++k) {
      float4 w = w24[k], v = h4[k];
      a2 += w.x * v.x + w.y * v.y + w.z * v.z + w.w * v.w;
    }
  }
  a2 = fmaxf(a2, 0.f);
  a2 = tf_keep(k2a, k2b, idx) ? a2 * 2.f : 0.f;
  xs[((size_t)b << 8) + j] = a2;
}

__global__ __launch_bounds__(128) void k_procmem(const float* __restrict__ memory,
    const float* __restrict__ wmem, float* __restrict__ pm) {
  int b = blockIdx.x / TIN, tt = blockIdx.x % TIN;
  int d = threadIdx.x;
  __shared__ __align__(16) float m_s[ENC];
  for (int k = d; k < ENC; k += 128) m_s[k] = memory[((size_t)b * TIN + tt) * ENC + k];
  __syncthreads();
  float a = 0.f;
  const float4* w4 = (const float4*)(wmem + (size_t)d * ENC);
  const float4* m4 = (const float4*)m_s;
  #pragma unroll 8
  for (int k = 0; k < ENC / 4; ++k) {
    float4 w = w4[k], v = m4[k];
    a += w.x * v.x + w.y * v.y + w.z * v.z + w.w * v.w;
  }
  pm[((size_t)b * TIN + tt) * ATTD + d] = a;
}

// Batched gate GEMM: part[ks][b][col] = sum over this block's K-range of
// W[col][k] * X[b][k], where virtual K = [in1 | in2 | in3] and
// W = [wih (wihK) | whh (1024)].  Tile: 256 cols x 64 b, 8x8 per thread.
__global__ __launch_bounds__(256) void k_gates(
    const float* __restrict__ in1, int L1,
    const float* __restrict__ in2, int L2,
    const float* __restrict__ in3,
    const float* __restrict__ wih, int wihK,
    const float* __restrict__ whh,
    float* __restrict__ part, int nch) {
  int ctile = blockIdx.x;            // cols base = ctile*256
  int ks = blockIdx.y;
  int tid = threadIdx.x;
  int cg = tid & 31, bg = tid >> 5;  // c0 = cg*8, b0 = bg*8
  __shared__ float xin_s[64 * 68];
  __shared__ float w_s[64 * 264];
  float acc[8][8];
  #pragma unroll
  for (int i = 0; i < 8; ++i)
    #pragma unroll
    for (int j = 0; j < 8; ++j) acc[i][j] = 0.f;

  int c_begin = (ks * nch) / KSPLIT, c_end = ((ks + 1) * nch) / KSPLIT;
  for (int cc = c_begin; cc < c_end; ++cc) {
    int k0 = cc * 64;
    const float* src; int sl, so;
    if (k0 < L1)            { src = in1; sl = L1;   so = k0; }
    else if (k0 < L1 + L2)  { src = in2; sl = L2;   so = k0 - L1; }
    else                    { src = in3; sl = 1024; so = k0 - L1 - L2; }
    const float* wsrc; int wl, wo;
    if (k0 < wihK) { wsrc = wih; wl = wihK; wo = k0; }
    else           { wsrc = whh; wl = 1024; wo = k0 - wihK; }

    __syncthreads();
    #pragma unroll
    for (int i = 0; i < 16; ++i) {           // input 64x64 -> xin_s[kk][b]
      int idx = tid + 256 * i;
      int b = idx >> 6, kk = idx & 63;
      xin_s[kk * 68 + b] = src[(size_t)b * sl + so + kk];
    }
    #pragma unroll 8
    for (int i = 0; i < 64; ++i) {           // weights 256c x 64k -> w_s[kk][c]
      int idx = tid + 256 * i;
      int c = idx >> 6, kk = idx & 63;
      w_s[kk * 264 + c] = wsrc[(size_t)(ctile * 256 + c) * wl + wo + kk];
    }
    __syncthreads();
    #pragma unroll 2
    for (int kk = 0; kk < 64; ++kk) {
      float4 x0 = *(const float4*)&xin_s[kk * 68 + bg * 8];
      float4 x1 = *(const float4*)&xin_s[kk * 68 + bg * 8 + 4];
      float4 w0 = *(const float4*)&w_s[kk * 264 + cg * 8];
      float4 w1 = *(const float4*)&w_s[kk * 264 + cg * 8 + 4];
      float xr[8] = {x0.x, x0.y, x0.z, x0.w, x1.x, x1.y, x1.z, x1.w};
      float wr[8] = {w0.x, w0.y, w0.z, w0.w, w1.x, w1.y, w1.z, w1.w};
      #pragma unroll
      for (int i = 0; i < 8; ++i)
        #pragma unroll
        for (int j = 0; j < 8; ++j) acc[i][j] += xr[i] * wr[j];
    }
  }
  #pragma unroll
  for (int i = 0; i < 8; ++i) {
    float* dst = part + ((size_t)ks * B_ + (bg * 8 + i)) * G4 + ctile * 256 + cg * 8;
    *(float4*)dst       = make_float4(acc[i][0], acc[i][1], acc[i][2], acc[i][3]);
    *(float4*)(dst + 4) = make_float4(acc[i][4], acc[i][5], acc[i][6], acc[i][7]);
  }
}

// per-b: finish att LSTM (sum KSPLIT partials), pq, conv, energies, softmax, ctx
__global__ __launch_bounds__(256) void k_attention(
    const float* __restrict__ part, float* __restrict__ hatt, float* __restrict__ catt,
    float* __restrict__ aw, float* __restrict__ awc, float* __restrict__ ctx,
    const float* __restrict__ pm, const float* __restrict__ memory,
    const float* __restrict__ wq, const float* __restrict__ wv,
    const float* __restrict__ wconv, const float* __restrict__ wloc,
    const float* __restrict__ bih, const float* __restrict__ bhh,
    const int* __restrict__ memlen, float* __restrict__ out_align, int t) {
  int b = blockIdx.x, tid = threadIdx.x;
  __shared__ float h_s[RNN];
  __shared__ float aw_s[TIN], awc_s[TIN];
  __shared__ float loc_s[LOCF * TIN];
  __shared__ float pq_s[ATTD];
  __shared__ float e2_s[2 * TIN];
  __shared__ float red[256];

  for (int r = 0; r < 4; ++r) {
    int j = tid + 256 * r;
    float ig = bih[j] + bhh[j];
    float fg = bih[RNN + j] + bhh[RNN + j];
    float gg = bih[2 * RNN + j] + bhh[2 * RNN + j];
    float og = bih[3 * RNN + j] + bhh[3 * RNN + j];
    #pragma unroll
    for (int ks = 0; ks < KSPLIT; ++ks) {
      const float* pr = part + ((size_t)ks * B_ + b) * G4;
      ig += pr[j]; fg += pr[RNN + j]; gg += pr[2 * RNN + j]; og += pr[3 * RNN + j];
    }
    float c = sigf(fg) * catt[(size_t)b * RNN + j] + sigf(ig) * tanhf(gg);
    float h = sigf(og) * tanhf(c);
    catt[(size_t)b * RNN + j] = c;
    hatt[(size_t)b * RNN + j] = h;
    h_s[j] = h;
  }
  for (int k = tid; k < TIN; k += 256) { aw_s[k] = aw[(size_t)b * TIN + k]; awc_s[k] = awc[(size_t)b * TIN + k]; }
  __syncthreads();

  {
    int d = tid & 127, hf = tid >> 7;
    float a = 0.f;
    const float* wr = wq + (size_t)d * RNN + hf * 512;
    const float* hr = h_s + hf * 512;
    #pragma unroll 8
    for (int k = 0; k < 512; ++k) a += hr[k] * wr[k];
    red[tid] = a;
  }
  __syncthreads();
  if (tid < ATTD) pq_s[tid] = red[tid] + red[tid + 128];

  for (int task = tid; task < LOCF * TIN; task += 256) {
    int f = task / TIN, tt = task % TIN;
    float a = 0.f;
    #pragma unroll
    for (int k = 0; k < LOCK; ++k) {
      int s = tt + k - 15;
      if (s >= 0 && s < TIN)
        a += aw_s[s] * wconv[f * (2 * LOCK) + k] + awc_s[s] * wconv[f * (2 * LOCK) + LOCK + k];
    }
    loc_s[task] = a;
  }
  __syncthreads();

  for (int task = tid; task < 2 * TIN; task += 256) {
    int hf = task / TIN, tt = task % TIN;
    float acc = 0.f;
    const float* pmr = pm + ((size_t)b * TIN + tt) * ATTD;
    for (int d = hf * 64; d < hf * 64 + 64; ++d) {
      float pl = 0.f;
      #pragma unroll
      for (int f = 0; f < LOCF; ++f) pl += loc_s[f * TIN + tt] * wloc[d * LOCF + f];
      acc += tanhf(pmr[d] + pq_s[d] + pl) * wv[d];
    }
    e2_s[task] = acc;
  }
  __syncthreads();

  int len = memlen[b];
  float ev = -3.0e38f;
  if (tid < TIN) ev = (tid < len) ? (e2_s[tid] + e2_s[TIN + tid]) : -1.0e9f;
  red[tid] = ev;
  __syncthreads();
  for (int s = 128; s > 0; s >>= 1) { if (tid < s) red[tid] = fmaxf(red[tid], red[tid + s]); __syncthreads(); }
  float m = red[0];
  __syncthreads();
  float p = (tid < TIN) ? __expf(ev - m) : 0.f;
  red[tid] = p;
  __syncthreads();
  for (int s = 128; s > 0; s >>= 1) { if (tid < s) red[tid] += red[tid + s]; __syncthreads(); }
  float inv = 1.f / red[0];
  __syncthreads();
  if (tid < TIN) {
    float a = p * inv;
    aw[(size_t)b * TIN + tid] = a;
    awc[(size_t)b * TIN + tid] = awc_s[tid] + a;
    out_align[((size_t)b * TOUT + t) * TIN + tid] = a;
    aw_s[tid] = a;
  }
  __syncthreads();

  for (int ee = tid; ee < ENC; ee += 256) {
    float a = 0.f;
    for (int tt = 0; tt < TIN; ++tt) a += aw_s[tt] * memory[((size_t)b * TIN + tt) * ENC + ee];
    ctx[(size_t)b * ENC + ee] = a;
  }
}

// per-b: finish dec LSTM (sum KSPLIT partials), mel + gate projections
__global__ __launch_bounds__(256) void k_outphase(
    const float* __restrict__ part, const float* __restrict__ ctx,
    float* __restrict__ hdec, float* __restrict__ cdec,
    const float* __restrict__ bih, const float* __restrict__ bhh,
    const float* __restrict__ wproj, const float* __restrict__ bproj,
    const float* __restrict__ wgate, const float* __restrict__ bgate,
    float* __restrict__ out, int t) {
  int b = blockIdx.x, tid = threadIdx.x;
  __shared__ float dha_s[RNN + ENC];
  __shared__ float red[256];
  for (int r = 0; r < 4; ++r) {
    int j = tid + 256 * r;
    float ig = bih[j] + bhh[j];
    float fg = bih[RNN + j] + bhh[RNN + j];
    float gg = bih[2 * RNN + j] + bhh[2 * RNN + j];
    float og = bih[3 * RNN + j] + bhh[3 * RNN + j];
    #pragma unroll
    for (int ks = 0; ks < KSPLIT; ++ks) {
      const float* pr = part + ((size_t)ks * B_ + b) * G4;
      ig += pr[j]; fg += pr[RNN + j]; gg += pr[2 * RNN + j]; og += pr[3 * RNN + j];
    }
    float c = sigf(fg) * cdec[(size_t)b * RNN + j] + sigf(ig) * tanhf(gg);
    float h = sigf(og) * tanhf(c);
    cdec[(size_t)b * RNN + j] = c;
    hdec[(size_t)b * RNN + j] = h;
    dha_s[j] = h;
  }
  for (int k = tid; k < ENC; k += 256) dha_s[RNN + k] = ctx[(size_t)b * ENC + k];
  __syncthreads();
  float mp = 0.f;
  if (tid < 2 * NMEL) {
    int m = tid % NMEL, hf = tid / NMEL;
    const float* wr = wproj + (size_t)m * (RNN + ENC) + hf * 768;
    const float* dr = dha_s + hf * 768;
    #pragma unroll 8
    for (int k = 0; k < 768; ++k) mp += dr[k] * wr[k];
  }
  red[tid] = mp;
  __syncthreads();
  if (tid < NMEL) {
    float mel = red[tid] + red[tid + NMEL] + bproj[tid];
    out[((size_t)b * NMEL + tid) * TOUT + t] = mel;
  }
  __syncthreads();
  float g = 0.f;
  for (int k = tid; k < RNN + ENC; k += 256) g += dha_s[k] * wgate[k];
  red[tid] = g;
  __syncthreads();
  for (int s = 128; s > 0; s >>= 1) { if (tid < s) red[tid] += red[tid + s]; __syncthreads(); }
  if (tid == 0) out[(size_t)2048000 + (size_t)b * TOUT + t] = red[0] + bgate[0];
}

// ---------------- host launcher (full 400 steps) ----------------
extern "C" void kernel_launch(void* const* d_in, const int* in_sizes, int n_in,
                              void* d_out, int out_size, void* d_ws, size_t ws_size,
                              hipStream_t stream) {
  (void)in_sizes; (void)n_in; (void)out_size; (void)ws_size;
  const float* memory  = (const float*)d_in[0];
  const float* dec     = (const float*)d_in[1];
  const int*   mlen    = (const int*)d_in[2];
  const float* w1      = (const float*)d_in[3];
  const float* w2      = (const float*)d_in[4];
  const float* wih_att = (const float*)d_in[5];
  const float* whh_att = (const float*)d_in[6];
  const float* bih_att = (const float*)d_in[7];
  const float* bhh_att = (const float*)d_in[8];
  const float* wq      = (const float*)d_in[9];
  const float* wmem    = (const float*)d_in[10];
  const float* wv      = (const float*)d_in[11];
  const float* wconv   = (const float*)d_in[12];
  const float* wloc    = (const float*)d_in[13];
  const float* wih_dec = (const float*)d_in[14];
  const float* whh_dec = (const float*)d_in[15];
  const float* bih_dec = (const float*)d_in[16];
  const float* bhh_dec = (const float*)d_in[17];
  const float* wproj   = (const float*)d_in[18];
  const float* bproj   = (const float*)d_in[19];
  const float* wgate   = (const float*)d_in[20];
  const float* bgate   = (const float*)d_in[21];
  float* out = (float*)d_out;
  float* ws  = (float*)d_ws;

  // dropout keys from jax.random.split(jax.random.key(42)); key = (0, 42)
  uint32_t dk1a, dk1b, dk2a, dk2b;
#if SPLIT_MODE == 0
  tf2x32(0u, 42u, 0u, 0u, &dk1a, &dk1b);
  tf2x32(0u, 42u, 0u, 1u, &dk2a, &dk2b);
#else
  uint32_t a0, b0, a1, b1;
  tf2x32(0u, 42u, 0u, 2u, &a0, &b0);
  tf2x32(0u, 42u, 1u, 3u, &a1, &b1);
  dk1a = a0; dk1b = a1; dk2a = b0; dk2b = b1;
#endif

  float* pm   = ws + OFF_PM;
  float* xs   = ws + OFF_XS;
  float* hatt = ws + OFF_HATT; float* catt = ws + OFF_CATT;
  float* hdec = ws + OFF_HDEC; float* cdec = ws + OFF_CDEC;
  float* ctxp = ws + OFF_CTX;
  float* aw   = ws + OFF_AW;   float* awc  = ws + OFF_AWC;
  float* part = ws + OFF_PART;

  int nstate = B_ * (PRE + 4 * RNN + ENC + 2 * TIN);   // xs..awc contiguous
  k_init<<<(nstate + 255) / 256, 256, 0, stream>>>(xs, nstate);
  k_procmem<<<B_ * TIN, 128, 0, stream>>>(memory, wmem, pm);

  float* out_align = out + 2073600;   // 64*80*400 + 64*400
  for (int t = 0; t < TOUT; ++t) {
    k_prenet_step<<<B_, 256, 0, stream>>>(dec, w1, w2, xs, dk1a, dk1b, dk2a, dk2b, t);
    // att gates: K = [xs(256) | ctx(512) | hatt(1024)], wih K=768, 28 chunks
    k_gates<<<dim3(16, KSPLIT), 256, 0, stream>>>(xs, PRE, ctxp, ENC, hatt,
                                                  wih_att, PRE + ENC, whh_att,
                                                  part, 28);
    k_attention<<<B_, 256, 0, stream>>>(part, hatt, catt, aw, awc, ctxp, pm, memory,
                                        wq, wv, wconv, wloc, bih_att, bhh_att,
                                        mlen, out_align, t);
    // dec gates: K = [hatt(1024) | ctx(512) | hdec(1024)], wih K=1536, 40 chunks
    k_gates<<<dim3(16, KSPLIT), 256, 0, stream>>>(hatt, RNN, ctxp, ENC, hdec,
                                                  wih_dec, RNN + ENC, whh_dec,
                                                  part, 40);
    k_outphase<<<B_, 256, 0, stream>>>(part, ctxp, hdec, cdec, bih_dec, bhh_dec,
                                       wproj, bproj, wgate, bgate, out, t);
  }
}

// Round 15
// 68446.307 us; speedup vs baseline: 4.0645x; 1.7010x over previous
//
#include <hip/hip_runtime.h>
#include <hip/hip_bf16.h>
#include <stdint.h>
#include <stddef.h>

// ============================================================================
// ROUND 15: occupancy + launch-count attack.
//  - k_gates: 128-col tiles, grid(32,16)=512 blocks, LDS 51KB -> 2 blocks/CU
//    (8 waves/CU vs 4), w_s stride 132 (4-way LDS conflict vs 8-way).
//  - k_attention / k_outphase: 512 threads (8 waves/CU), energies split 4-way
//    in d, wloc/wconv staged in LDS, unrolled latency-critical loops.
//  - prenet fused into k_outphase (computes x_{t+1}); 4 launches/step.
// ============================================================================
#define SPLIT_MODE 0
#define BITS_MODE  0
#define KSPLIT 16

#define B_    64
#define TIN   200
#define TOUT  400
#define ENC   512
#define NMEL  80
#define PRE   256
#define RNN   1024
#define G4    4096
#define ATTD  128
#define LOCF  32
#define LOCK  31
#define MSIZE 6569984u   // 401*64*256

// ---------------- threefry2x32-20 (hand-verified vs split(PRNGKey(0))) ----------------
__host__ __device__ inline void tf2x32(uint32_t k0, uint32_t k1, uint32_t x0, uint32_t x1,
                                       uint32_t* o0, uint32_t* o1) {
  uint32_t k2 = k0 ^ k1 ^ 0x1BD11BDAu;
#define TFROT(v, r) (((v) << (r)) | ((v) >> (32 - (r))))
#define TFR(r) { x0 += x1; x1 = TFROT(x1, r); x1 ^= x0; }
  x0 += k0; x1 += k1;
  TFR(13) TFR(15) TFR(26) TFR(6)  x0 += k1; x1 += k2 + 1u;
  TFR(17) TFR(29) TFR(16) TFR(24) x0 += k2; x1 += k0 + 2u;
  TFR(13) TFR(15) TFR(26) TFR(6)  x0 += k0; x1 += k1 + 3u;
  TFR(17) TFR(29) TFR(16) TFR(24) x0 += k1; x1 += k2 + 4u;
  TFR(13) TFR(15) TFR(26) TFR(6)  x0 += k2; x1 += k0 + 5u;
  *o0 = x0; *o1 = x1;
#undef TFR
#undef TFROT
}

__device__ inline bool tf_keep(uint32_t ka, uint32_t kb, uint32_t idx) {
#if BITS_MODE == 0
  uint32_t a, b; tf2x32(ka, kb, 0u, idx, &a, &b);
  return (((a ^ b) >> 31) == 0u);      // partitionable x32: bits = o0 ^ o1
#else
  const uint32_t HALF = MSIZE / 2u;
  uint32_t a, b;
  if (idx < HALF) { tf2x32(ka, kb, idx, idx + HALF, &a, &b); return ((a >> 31) == 0u); }
  else            { tf2x32(ka, kb, idx - HALF, idx, &a, &b); return ((b >> 31) == 0u); }
#endif
}

__device__ inline float sigf(float x) { return 1.f / (1.f + __expf(-x)); }

// ---------------- workspace layout (floats) — ~25 MB ----------------
static const size_t OFF_PM   = 0;                                    // 64*200*128
static const size_t OFF_XS   = OFF_PM   + (size_t)B_ * TIN * ATTD;   // 64*256
static const size_t OFF_HATT = OFF_XS   + (size_t)B_ * PRE;
static const size_t OFF_CATT = OFF_HATT + (size_t)B_ * RNN;
static const size_t OFF_HDEC = OFF_CATT + (size_t)B_ * RNN;
static const size_t OFF_CDEC = OFF_HDEC + (size_t)B_ * RNN;
static const size_t OFF_CTX  = OFF_CDEC + (size_t)B_ * RNN;
static const size_t OFF_AW   = OFF_CTX  + (size_t)B_ * ENC;
static const size_t OFF_AWC  = OFF_AW   + (size_t)B_ * TIN;
static const size_t OFF_PART = OFF_AWC  + (size_t)B_ * TIN;          // 16*64*4096

// ---------------- kernels ----------------
__global__ __launch_bounds__(256) void k_init(float* s, int n) {
  int i = blockIdx.x * 256 + threadIdx.x;
  if (i < n) s[i] = 0.f;
}

__global__ __launch_bounds__(128) void k_procmem(const float* __restrict__ memory,
    const float* __restrict__ wmem, float* __restrict__ pm) {
  int b = blockIdx.x / TIN, tt = blockIdx.x % TIN;
  int d = threadIdx.x;
  __shared__ __align__(16) float m_s[ENC];
  for (int k = d; k < ENC; k += 128) m_s[k] = memory[((size_t)b * TIN + tt) * ENC + k];
  __syncthreads();
  float a = 0.f;
  const float4* w4 = (const float4*)(wmem + (size_t)d * ENC);
  const float4* m4 = (const float4*)m_s;
  #pragma unroll 8
  for (int k = 0; k < ENC / 4; ++k) {
    float4 w = w4[k], v = m4[k];
    a += w.x * v.x + w.y * v.y + w.z * v.z + w.w * v.w;
  }
  pm[((size_t)b * TIN + tt) * ATTD + d] = a;
}

// Batched gate GEMM: 128-col tiles, grid (32, KSPLIT). Per thread 8b x 4c.
#define WSTR 132
__global__ __launch_bounds__(256) void k_gates(
    const float* __restrict__ in1, int L1,
    const float* __restrict__ in2, int L2,
    const float* __restrict__ in3,
    const float* __restrict__ wih, int wihK,
    const float* __restrict__ whh,
    float* __restrict__ part, int nch) {
  int ctile = blockIdx.x;            // cols base = ctile*128
  int ks = blockIdx.y;
  int tid = threadIdx.x;
  int cg = tid & 31, bg = tid >> 5;  // c0 = cg*4, b0 = bg*8
  __shared__ float xin_s[64 * 68];
  __shared__ float w_s[64 * WSTR];
  float acc[8][4];
  #pragma unroll
  for (int i = 0; i < 8; ++i)
    #pragma unroll
    for (int j = 0; j < 4; ++j) acc[i][j] = 0.f;

  int c_begin = (ks * nch) / KSPLIT, c_end = ((ks + 1) * nch) / KSPLIT;
  for (int cc = c_begin; cc < c_end; ++cc) {
    int k0 = cc * 64;
    const float* src; int sl, so;
    if (k0 < L1)            { src = in1; sl = L1;   so = k0; }
    else if (k0 < L1 + L2)  { src = in2; sl = L2;   so = k0 - L1; }
    else                    { src = in3; sl = 1024; so = k0 - L1 - L2; }
    const float* wsrc; int wl, wo;
    if (k0 < wihK) { wsrc = wih; wl = wihK; wo = k0; }
    else           { wsrc = whh; wl = 1024; wo = k0 - wihK; }

    __syncthreads();
    #pragma unroll
    for (int i = 0; i < 16; ++i) {           // input 64x64 -> xin_s[kk][b]
      int idx = tid + 256 * i;
      int b = idx >> 6, kk = idx & 63;
      xin_s[kk * 68 + b] = src[(size_t)b * sl + so + kk];
    }
    #pragma unroll
    for (int i = 0; i < 8; ++i) {            // weights 128c x 64k (float4 loads)
      int idx = tid + 256 * i;
      int c = idx >> 4, kq = idx & 15;
      float4 w = *(const float4*)&wsrc[(size_t)(ctile * 128 + c) * wl + wo + kq * 4];
      w_s[(kq * 4 + 0) * WSTR + c] = w.x;
      w_s[(kq * 4 + 1) * WSTR + c] = w.y;
      w_s[(kq * 4 + 2) * WSTR + c] = w.z;
      w_s[(kq * 4 + 3) * WSTR + c] = w.w;
    }
    __syncthreads();
    #pragma unroll 4
    for (int kk = 0; kk < 64; ++kk) {
      float4 w  = *(const float4*)&w_s[kk * WSTR + cg * 4];
      float4 x0 = *(const float4*)&xin_s[kk * 68 + bg * 8];
      float4 x1 = *(const float4*)&xin_s[kk * 68 + bg * 8 + 4];
      float xr[8] = {x0.x, x0.y, x0.z, x0.w, x1.x, x1.y, x1.z, x1.w};
      float wr[4] = {w.x, w.y, w.z, w.w};
      #pragma unroll
      for (int i = 0; i < 8; ++i)
        #pragma unroll
        for (int j = 0; j < 4; ++j) acc[i][j] += xr[i] * wr[j];
    }
  }
  #pragma unroll
  for (int i = 0; i < 8; ++i) {
    float* dst = part + ((size_t)ks * B_ + (bg * 8 + i)) * G4 + ctile * 128 + cg * 4;
    *(float4*)dst = make_float4(acc[i][0], acc[i][1], acc[i][2], acc[i][3]);
  }
}

// per-b (512 thr): finish att LSTM, pq, conv, energies(4-way d), softmax, ctx
__global__ __launch_bounds__(512) void k_attention(
    const float* __restrict__ part, float* __restrict__ hatt, float* __restrict__ catt,
    float* __restrict__ aw, float* __restrict__ awc, float* __restrict__ ctx,
    const float* __restrict__ pm, const float* __restrict__ memory,
    const float* __restrict__ wq, const float* __restrict__ wv,
    const float* __restrict__ wconv, const float* __restrict__ wloc,
    const float* __restrict__ bih, const float* __restrict__ bhh,
    const int* __restrict__ memlen, float* __restrict__ out_align, int t) {
  int b = blockIdx.x, tid = threadIdx.x;
  __shared__ float h_s[RNN];
  __shared__ float aw_s[TIN], awc_s[TIN];
  __shared__ float loc_s[LOCF * TIN];
  __shared__ float pq_s[ATTD];
  __shared__ float e4_s[4 * TIN];
  __shared__ float red[512];
  __shared__ float wl_s[ATTD * LOCF];
  __shared__ float wc_s[LOCF * 2 * LOCK];

  for (int k = tid; k < ATTD * LOCF; k += 512) wl_s[k] = wloc[k];
  for (int k = tid; k < LOCF * 2 * LOCK; k += 512) wc_s[k] = wconv[k];

  #pragma unroll
  for (int r = 0; r < 2; ++r) {
    int j = tid + 512 * r;
    float ig = bih[j] + bhh[j];
    float fg = bih[RNN + j] + bhh[RNN + j];
    float gg = bih[2 * RNN + j] + bhh[2 * RNN + j];
    float og = bih[3 * RNN + j] + bhh[3 * RNN + j];
    #pragma unroll
    for (int ks = 0; ks < KSPLIT; ++ks) {
      const float* pr = part + ((size_t)ks * B_ + b) * G4;
      ig += pr[j]; fg += pr[RNN + j]; gg += pr[2 * RNN + j]; og += pr[3 * RNN + j];
    }
    float c = sigf(fg) * catt[(size_t)b * RNN + j] + sigf(ig) * tanhf(gg);
    float h = sigf(og) * tanhf(c);
    catt[(size_t)b * RNN + j] = c;
    hatt[(size_t)b * RNN + j] = h;
    h_s[j] = h;
  }
  for (int k = tid; k < TIN; k += 512) { aw_s[k] = aw[(size_t)b * TIN + k]; awc_s[k] = awc[(size_t)b * TIN + k]; }
  __syncthreads();

  // pq = h @ wq.T  (4-way K split)
  {
    int d = tid & 127, hf = tid >> 7;
    float a = 0.f;
    const float* wr = wq + (size_t)d * RNN + hf * 256;
    const float* hr = h_s + hf * 256;
    #pragma unroll 8
    for (int k = 0; k < 256; ++k) a += hr[k] * wr[k];
    red[tid] = a;
  }
  __syncthreads();
  if (tid < ATTD) pq_s[tid] = red[tid] + red[tid + 128] + red[tid + 256] + red[tid + 384];

  // location conv
  for (int task = tid; task < LOCF * TIN; task += 512) {
    int f = task / TIN, tt = task % TIN;
    float a = 0.f;
    #pragma unroll
    for (int k = 0; k < LOCK; ++k) {
      int s = tt + k - 15;
      if (s >= 0 && s < TIN)
        a += aw_s[s] * wc_s[f * (2 * LOCK) + k] + awc_s[s] * wc_s[f * (2 * LOCK) + LOCK + k];
    }
    loc_s[task] = a;
  }
  __syncthreads();

  // energies, 4-way split over d
  for (int task = tid; task < 4 * TIN; task += 512) {
    int hf = task / TIN, tt = task - hf * TIN;
    float acc = 0.f;
    const float* pmr = pm + ((size_t)b * TIN + tt) * ATTD;
    #pragma unroll 4
    for (int d = hf * 32; d < hf * 32 + 32; ++d) {
      float pl = 0.f;
      #pragma unroll
      for (int f = 0; f < LOCF; ++f) pl += loc_s[f * TIN + tt] * wl_s[d * LOCF + f];
      acc += tanhf(pmr[d] + pq_s[d] + pl) * wv[d];
    }
    e4_s[task] = acc;
  }
  __syncthreads();

  // masked softmax over tt
  int len = memlen[b];
  float ev = -3.0e38f;
  if (tid < TIN)
    ev = (tid < len) ? (e4_s[tid] + e4_s[TIN + tid] + e4_s[2 * TIN + tid] + e4_s[3 * TIN + tid])
                     : -1.0e9f;
  red[tid] = ev;
  __syncthreads();
  for (int s = 256; s > 0; s >>= 1) { if (tid < s) red[tid] = fmaxf(red[tid], red[tid + s]); __syncthreads(); }
  float m = red[0];
  __syncthreads();
  float p = (tid < TIN) ? __expf(ev - m) : 0.f;
  red[tid] = p;
  __syncthreads();
  for (int s = 256; s > 0; s >>= 1) { if (tid < s) red[tid] += red[tid + s]; __syncthreads(); }
  float inv = 1.f / red[0];
  __syncthreads();
  if (tid < TIN) {
    float a = p * inv;
    aw[(size_t)b * TIN + tid] = a;
    awc[(size_t)b * TIN + tid] = awc_s[tid] + a;
    out_align[((size_t)b * TOUT + t) * TIN + tid] = a;
    aw_s[tid] = a;
  }
  __syncthreads();

  // ctx: one ee per thread
  {
    float a = 0.f;
    const float* mr = memory + (size_t)b * TIN * ENC + tid;
    #pragma unroll 8
    for (int tt = 0; tt < TIN; ++tt) a += aw_s[tt] * mr[(size_t)tt * ENC];
    ctx[(size_t)b * ENC + tid] = a;
  }
}

// per-b (512 thr): finish dec LSTM, mel + gate projections, prenet for t+1
__global__ __launch_bounds__(512) void k_outphase(
    const float* __restrict__ part, const float* __restrict__ ctx,
    float* __restrict__ hdec, float* __restrict__ cdec,
    const float* __restrict__ bih, const float* __restrict__ bhh,
    const float* __restrict__ wproj, const float* __restrict__ bproj,
    const float* __restrict__ wgate, const float* __restrict__ bgate,
    float* __restrict__ out,
    const float* __restrict__ dec, const float* __restrict__ w1,
    const float* __restrict__ w2, float* __restrict__ xs,
    uint32_t k1a, uint32_t k1b, uint32_t k2a, uint32_t k2b, int t) {
  int b = blockIdx.x, tid = threadIdx.x;
  __shared__ float dha_s[RNN + ENC];
  __shared__ float red[512];
  __shared__ __align__(16) float in_s[NMEL];
  __shared__ __align__(16) float h2_s[PRE];
  #pragma unroll
  for (int r = 0; r < 2; ++r) {
    int j = tid + 512 * r;
    float ig = bih[j] + bhh[j];
    float fg = bih[RNN + j] + bhh[RNN + j];
    float gg = bih[2 * RNN + j] + bhh[2 * RNN + j];
    float og = bih[3 * RNN + j] + bhh[3 * RNN + j];
    #pragma unroll
    for (int ks = 0; ks < KSPLIT; ++ks) {
      const float* pr = part + ((size_t)ks * B_ + b) * G4;
      ig += pr[j]; fg += pr[RNN + j]; gg += pr[2 * RNN + j]; og += pr[3 * RNN + j];
    }
    float c = sigf(fg) * cdec[(size_t)b * RNN + j] + sigf(ig) * tanhf(gg);
    float h = sigf(og) * tanhf(c);
    cdec[(size_t)b * RNN + j] = c;
    hdec[(size_t)b * RNN + j] = h;
    dha_s[j] = h;
  }
  for (int k = tid; k < ENC; k += 512) dha_s[RNN + k] = ctx[(size_t)b * ENC + k];
  if (t + 1 < TOUT && tid < NMEL)
    in_s[tid] = dec[((size_t)b * NMEL + tid) * TOUT + t];
  __syncthreads();
  // mel: 320 tasks (m, K-quarter of 384)
  float mp = 0.f;
  if (tid < 4 * NMEL) {
    int m = tid % NMEL, hf = tid / NMEL;
    const float* wr = wproj + (size_t)m * (RNN + ENC) + hf * 384;
    const float* dr = dha_s + hf * 384;
    #pragma unroll 8
    for (int k = 0; k < 384; ++k) mp += dr[k] * wr[k];
  }
  red[tid] = mp;
  __syncthreads();
  if (tid < NMEL) {
    float mel = red[tid] + red[tid + NMEL] + red[tid + 2 * NMEL] + red[tid + 3 * NMEL] + bproj[tid];
    out[((size_t)b * NMEL + tid) * TOUT + t] = mel;
  }
  __syncthreads();
  float g = 0.f;
  for (int k = tid; k < RNN + ENC; k += 512) g += dha_s[k] * wgate[k];
  red[tid] = g;
  __syncthreads();
  for (int s = 256; s > 0; s >>= 1) { if (tid < s) red[tid] += red[tid + s]; __syncthreads(); }
  if (tid == 0) out[(size_t)2048000 + (size_t)b * TOUT + t] = red[0] + bgate[0];

  // ---- prenet for step t+1 ----
  if (t + 1 < TOUT) {
    int tn = t + 1;
    if (tid < PRE) {
      float a = 0.f;
      const float4* w14 = (const float4*)(w1 + (size_t)tid * NMEL);
      const float4* i4  = (const float4*)in_s;
      #pragma unroll
      for (int k = 0; k < NMEL / 4; ++k) {
        float4 w = w14[k], v = i4[k];
        a += w.x * v.x + w.y * v.y + w.z * v.z + w.w * v.w;
      }
      a = fmaxf(a, 0.f);
      uint32_t idx = (uint32_t)((tn * 64 + b) * 256 + tid);
      a = tf_keep(k1a, k1b, idx) ? a * 2.f : 0.f;
      h2_s[tid] = a;
    }
    __syncthreads();
    if (tid < PRE) {
      float a2 = 0.f;
      const float4* w24 = (const float4*)(w2 + (size_t)tid * PRE);
      const float4* h4  = (const float4*)h2_s;
      #pragma unroll 8
      for (int k = 0; k < PRE / 4; ++k) {
        float4 w = w24[k], v = h4[k];
        a2 += w.x * v.x + w.y * v.y + w.z * v.z + w.w * v.w;
      }
      a2 = fmaxf(a2, 0.f);
      uint32_t idx = (uint32_t)((tn * 64 + b) * 256 + tid);
      a2 = tf_keep(k2a, k2b, idx) ? a2 * 2.f : 0.f;
      xs[((size_t)b << 8) + tid] = a2;
    }
  }
}

// ---------------- host launcher (full 400 steps) ----------------
extern "C" void kernel_launch(void* const* d_in, const int* in_sizes, int n_in,
                              void* d_out, int out_size, void* d_ws, size_t ws_size,
                              hipStream_t stream) {
  (void)in_sizes; (void)n_in; (void)out_size; (void)ws_size;
  const float* memory  = (const float*)d_in[0];
  const float* dec     = (const float*)d_in[1];
  const int*   mlen    = (const int*)d_in[2];
  const float* w1      = (const float*)d_in[3];
  const float* w2      = (const float*)d_in[4];
  const float* wih_att = (const float*)d_in[5];
  const float* whh_att = (const float*)d_in[6];
  const float* bih_att = (const float*)d_in[7];
  const float* bhh_att = (const float*)d_in[8];
  const float* wq      = (const float*)d_in[9];
  const float* wmem    = (const float*)d_in[10];
  const float* wv      = (const float*)d_in[11];
  const float* wconv   = (const float*)d_in[12];
  const float* wloc    = (const float*)d_in[13];
  const float* wih_dec = (const float*)d_in[14];
  const float* whh_dec = (const float*)d_in[15];
  const float* bih_dec = (const float*)d_in[16];
  const float* bhh_dec = (const float*)d_in[17];
  const float* wproj   = (const float*)d_in[18];
  const float* bproj   = (const float*)d_in[19];
  const float* wgate   = (const float*)d_in[20];
  const float* bgate   = (const float*)d_in[21];
  float* out = (float*)d_out;
  float* ws  = (float*)d_ws;

  // dropout keys from jax.random.split(jax.random.key(42)); key = (0, 42)
  uint32_t dk1a, dk1b, dk2a, dk2b;
#if SPLIT_MODE == 0
  tf2x32(0u, 42u, 0u, 0u, &dk1a, &dk1b);
  tf2x32(0u, 42u, 0u, 1u, &dk2a, &dk2b);
#else
  uint32_t a0, b0, a1, b1;
  tf2x32(0u, 42u, 0u, 2u, &a0, &b0);
  tf2x32(0u, 42u, 1u, 3u, &a1, &b1);
  dk1a = a0; dk1b = a1; dk2a = b0; dk2b = b1;
#endif

  float* pm   = ws + OFF_PM;
  float* xs   = ws + OFF_XS;
  float* hatt = ws + OFF_HATT; float* catt = ws + OFF_CATT;
  float* hdec = ws + OFF_HDEC; float* cdec = ws + OFF_CDEC;
  float* ctxp = ws + OFF_CTX;
  float* aw   = ws + OFF_AW;   float* awc  = ws + OFF_AWC;
  float* part = ws + OFF_PART;

  int nstate = B_ * (PRE + 4 * RNN + ENC + 2 * TIN);   // xs..awc contiguous (xs=0 == x_0)
  k_init<<<(nstate + 255) / 256, 256, 0, stream>>>(xs, nstate);
  k_procmem<<<B_ * TIN, 128, 0, stream>>>(memory, wmem, pm);

  float* out_align = out + 2073600;   // 64*80*400 + 64*400
  for (int t = 0; t < TOUT; ++t) {
    // att gates: K = [xs(256) | ctx(512) | hatt(1024)], wih K=768, 28 chunks
    k_gates<<<dim3(32, KSPLIT), 256, 0, stream>>>(xs, PRE, ctxp, ENC, hatt,
                                                  wih_att, PRE + ENC, whh_att,
                                                  part, 28);
    k_attention<<<B_, 512, 0, stream>>>(part, hatt, catt, aw, awc, ctxp, pm, memory,
                                        wq, wv, wconv, wloc, bih_att, bhh_att,
                                        mlen, out_align, t);
    // dec gates: K = [hatt(1024) | ctx(512) | hdec(1024)], wih K=1536, 40 chunks
    k_gates<<<dim3(32, KSPLIT), 256, 0, stream>>>(hatt, RNN, ctxp, ENC, hdec,
                                                  wih_dec, RNN + ENC, whh_dec,
                                                  part, 40);
    k_outphase<<<B_, 512, 0, stream>>>(part, ctxp, hdec, cdec, bih_dec, bhh_dec,
                                       wproj, bproj, wgate, bgate, out,
                                       dec, w1, w2, xs, dk1a, dk1b, dk2a, dk2b, t);
  }
}